// Round 1
// baseline (8303.345 us; speedup 1.0000x reference)
//
#include <hip/hip_runtime.h>
#include <math.h>

// CausalVisionMamba — fp32 correctness-first implementation.
// B=4, L=3136(56x56), D_MODEL=384, D_INNER=768, D_STATE=16, DT_RANK=24, 4 layers.
// Workspace use: ~215 MB of d_ws (fp32 buffers).

namespace {
constexpr int NB = 4;
constexpr int SL = 3136;   // sequence length 56*56
constexpr int DM = 384;    // d_model
constexpr int DI = 768;    // d_inner
constexpr int DSN = 16;    // d_state
constexpr int DR = 24;     // dt_rank
constexpr int NLAYER = 4;
constexpr int NCLS = 1000;
constexpr int XPN = DR + 2 * DSN;  // 56
}

__device__ __forceinline__ float siluf(float x) { return x / (1.f + expf(-x)); }
__device__ __forceinline__ float softplusf(float x) {
  return fmaxf(x, 0.f) + log1pf(expf(-fabsf(x)));
}

// ---------------- patch embed: t[b][l][dm] ----------------
__global__ void k_patch(const float* __restrict__ x, const float* __restrict__ w,
                        const float* __restrict__ bias, float* __restrict__ t) {
  const int blk = blockIdx.x;  // b*SL + l
  const int b = blk / SL, l = blk % SL;
  const int hh = l / 56, ww = l % 56;
  __shared__ float patch[48];
  const int tid = threadIdx.x;
  if (tid < 48) {
    const int c = tid / 16, kh = (tid % 16) / 4, kw = tid % 4;
    patch[tid] = x[((size_t)(b * 3 + c) * 224 + (hh * 4 + kh)) * 224 + (ww * 4 + kw)];
  }
  __syncthreads();
  for (int dm = tid; dm < DM; dm += 128) {
    const float* wr = w + (size_t)dm * 48;
    float acc = bias[dm];
#pragma unroll
    for (int p = 0; p < 48; ++p) acc = fmaf(patch[p], wr[p], acc);
    t[((size_t)b * SL + l) * DM + dm] = acc;
  }
}

// ---------------- generic tiled fp32 GEMM: C = A[M,K] * W[N,K]^T ----------------
// EPI 0: plain write to out[m*56 + n], n < NCAP (x_proj -> dbl)
// EPI 1: in_proj split: n<DI -> transposed out[b][n][l] (xcT); n>=DI -> out2[m][n-DI] (res)
// EPI 2: dt_proj: softplus(acc + bias[n]) -> transposed out[b][n][l] (deltaT)
// EPI 3: out_proj: out[m*DM + n] += acc  (residual accumulate into t)
// ATRANS: A[m][k] = A[(b*K + k)*SL + l]  (A stored [B][K][L], for x_proj reading uT)
template <int EPI, bool ATRANS, bool KTAIL, int NCAP>
__global__ __launch_bounds__(256) void k_gemm(
    const float* __restrict__ A, const float* __restrict__ W,
    const float* __restrict__ bias, float* __restrict__ out,
    float* __restrict__ out2, int K, int lda) {
  __shared__ float sm[4352];  // staging: As[16][68] + Ws[16][68]; epilogue: Cs[64][68]
  const int tid = threadIdx.x;
  const int m0 = blockIdx.x * 64;
  const int n0 = blockIdx.y * 64;
  const int b = m0 / SL, l0 = m0 % SL;
  const int tm = tid >> 4, tn = tid & 15;
  float acc[4][4] = {};
  float* As = sm;
  float* Ws = sm + 16 * 68;

  const int nk = (K + 15) / 16;
  for (int kt = 0; kt < nk; ++kt) {
    const int k0 = kt * 16;
    if (ATRANS) {
      const int kk = tid >> 4;
      const int lq = (tid & 15) * 4;
      const float4 v = *(const float4*)&A[((size_t)(b * K + k0 + kk)) * SL + l0 + lq];
      *(float4*)&As[kk * 68 + lq] = v;
    } else {
      const int row = tid >> 2;
      const int kq = (tid & 3) * 4;
      const int kb = k0 + kq;
      float4 v = make_float4(0.f, 0.f, 0.f, 0.f);
      if (!KTAIL || kb < K) v = *(const float4*)&A[(size_t)(m0 + row) * lda + kb];
      As[(kq + 0) * 68 + row] = v.x;
      As[(kq + 1) * 68 + row] = v.y;
      As[(kq + 2) * 68 + row] = v.z;
      As[(kq + 3) * 68 + row] = v.w;
    }
    {
      const int row = tid >> 2;
      const int kq = (tid & 3) * 4;
      const int kb = k0 + kq;
      float4 v = make_float4(0.f, 0.f, 0.f, 0.f);
      const bool nok = (NCAP % 64 == 0) || (n0 + row < NCAP);
      if (nok && (!KTAIL || kb < K)) v = *(const float4*)&W[(size_t)(n0 + row) * K + kb];
      Ws[(kq + 0) * 68 + row] = v.x;
      Ws[(kq + 1) * 68 + row] = v.y;
      Ws[(kq + 2) * 68 + row] = v.z;
      Ws[(kq + 3) * 68 + row] = v.w;
    }
    __syncthreads();
#pragma unroll
    for (int kk = 0; kk < 16; ++kk) {
      const float4 av = *(const float4*)&As[kk * 68 + 4 * tm];
      const float4 wv = *(const float4*)&Ws[kk * 68 + 4 * tn];
      const float ax[4] = {av.x, av.y, av.z, av.w};
      const float wx[4] = {wv.x, wv.y, wv.z, wv.w};
#pragma unroll
      for (int i = 0; i < 4; ++i)
#pragma unroll
        for (int j = 0; j < 4; ++j) acc[i][j] = fmaf(ax[i], wx[j], acc[i][j]);
    }
    __syncthreads();
  }

  if (EPI == 0) {
#pragma unroll
    for (int i = 0; i < 4; ++i) {
      const size_t ro = (size_t)(m0 + 4 * tm + i) * 56;
#pragma unroll
      for (int j = 0; j < 4; ++j) {
        const int nn = n0 + 4 * tn + j;
        if (nn < NCAP) out[ro + nn] = acc[i][j];
      }
    }
  } else if (EPI == 3) {
#pragma unroll
    for (int i = 0; i < 4; ++i) {
      const size_t o = (size_t)(m0 + 4 * tm + i) * DM + n0 + 4 * tn;
      float4 c = *(float4*)&out[o];
      c.x += acc[i][0];
      c.y += acc[i][1];
      c.z += acc[i][2];
      c.w += acc[i][3];
      *(float4*)&out[o] = c;
    }
  } else {
    if (EPI == 1 && n0 >= DI) {
#pragma unroll
      for (int i = 0; i < 4; ++i) {
        const float4 c = make_float4(acc[i][0], acc[i][1], acc[i][2], acc[i][3]);
        *(float4*)&out2[(size_t)(m0 + 4 * tm + i) * DI + (n0 - DI) + 4 * tn] = c;
      }
    } else {
      // transpose epilogue through LDS -> out[b][n][l] coalesced along l
#pragma unroll
      for (int j = 0; j < 4; ++j) {
        const int nn = 4 * tn + j;
#pragma unroll
        for (int i = 0; i < 4; ++i) {
          float v = acc[i][j];
          if (EPI == 2) v = softplusf(v + bias[n0 + nn]);
          sm[nn * 68 + 4 * tm + i] = v;
        }
      }
      __syncthreads();
      const int row = tid >> 2;           // local n (0..63)
      const int seg = (tid & 3) * 16;     // l segment
      float* dst = out + ((size_t)(b * DI + n0 + row)) * SL + l0 + seg;
#pragma unroll
      for (int q = 0; q < 4; ++q) {
        *(float4*)&dst[q * 4] = *(const float4*)&sm[row * 68 + seg + q * 4];
      }
    }
  }
}

// ---------------- depthwise causal conv1d + bias + silu: uT[b][d][l] ----------------
__global__ void k_conv(const float* __restrict__ xcT, const float* __restrict__ cw,
                       const float* __restrict__ cb, float* __restrict__ uT) {
  const size_t idx = (size_t)blockIdx.x * 256 + threadIdx.x;
  const int l = (int)(idx % SL);
  const int bd = (int)(idx / SL);
  const int d = bd % DI;
  const float* row = xcT + (size_t)bd * SL;
  const float4 w = *(const float4*)&cw[d * 4];
  float acc = cb[d] + w.w * row[l];
  if (l >= 1) acc = fmaf(w.z, row[l - 1], acc);
  if (l >= 2) acc = fmaf(w.y, row[l - 2], acc);
  if (l >= 3) acc = fmaf(w.x, row[l - 3], acc);
  uT[idx] = siluf(acc);
}

// ---------------- selective scan (fused +u*Dp and *silu(res)) ----------------
// lane n = tid&15 holds state n of chain (b,d); 16 groups per 256-thread block.
__global__ __launch_bounds__(256) void k_scan(
    const float* __restrict__ deltaT, const float* __restrict__ uT,
    const float* __restrict__ dbl, const float* __restrict__ res,
    const float* __restrict__ A_log, const float* __restrict__ Dp,
    float* __restrict__ y) {
  const int tid = threadIdx.x;
  const int n = tid & 15, g = tid >> 4;
  const int gid = blockIdx.x * 16 + g;  // 0 .. NB*DI-1
  const int b = gid / DI, d = gid % DI;
  const float a2 = -expf(A_log[d * DSN + n]) * 1.44269504088896341f;  // A * log2(e)
  const float dp = Dp[d];
  const float* drow = deltaT + (size_t)gid * SL;
  const float* urow = uT + (size_t)gid * SL;
  const float* dblb = dbl + (size_t)b * SL * XPN;
  const float* resb = res + (size_t)b * SL * DI + d;
  float* yb = y + (size_t)b * SL * DI + d;
  float h = 0.f;
  for (int l0 = 0; l0 < SL; l0 += 8) {
    const float4 dv0 = *(const float4*)&drow[l0];
    const float4 dv1 = *(const float4*)&drow[l0 + 4];
    const float4 uv0 = *(const float4*)&urow[l0];
    const float4 uv1 = *(const float4*)&urow[l0 + 4];
    float Bv[8], Cv[8];
#pragma unroll
    for (int j = 0; j < 8; ++j) {
      Bv[j] = dblb[(size_t)(l0 + j) * XPN + DR + n];
      Cv[j] = dblb[(size_t)(l0 + j) * XPN + DR + DSN + n];
    }
    const float dvv[8] = {dv0.x, dv0.y, dv0.z, dv0.w, dv1.x, dv1.y, dv1.z, dv1.w};
    const float uvv[8] = {uv0.x, uv0.y, uv0.z, uv0.w, uv1.x, uv1.y, uv1.z, uv1.w};
#pragma unroll
    for (int j = 0; j < 8; ++j) {
      const float dl = dvv[j], ul = uvv[j];
      const float da = exp2f(dl * a2);
      h = fmaf(da, h, dl * ul * Bv[j]);
      float p = h * Cv[j];
      p += __shfl_xor(p, 1);
      p += __shfl_xor(p, 2);
      p += __shfl_xor(p, 4);
      p += __shfl_xor(p, 8);
      if (n == 0) {
        const float r = resb[(size_t)(l0 + j) * DI];
        yb[(size_t)(l0 + j) * DI] = (p + ul * dp) * siluf(r);
      }
    }
  }
}

// ---------------- RMS denom: rinv[b*SL+l] = 1/sqrt(mean(t^2)+eps) ----------------
__global__ void k_rinv(const float* __restrict__ t, float* __restrict__ rinv) {
  const int row = blockIdx.x;
  const float* tr = t + (size_t)row * DM;
  const int tid = threadIdx.x;  // 64
  float ss = 0.f;
#pragma unroll
  for (int k = 0; k < DM / 64; ++k) {
    const float v = tr[tid + k * 64];
    ss = fmaf(v, v, ss);
  }
  ss += __shfl_xor(ss, 1);
  ss += __shfl_xor(ss, 2);
  ss += __shfl_xor(ss, 4);
  ss += __shfl_xor(ss, 8);
  ss += __shfl_xor(ss, 16);
  ss += __shfl_xor(ss, 32);
  if (tid == 0) rinv[row] = 1.f / sqrtf(ss / DM + 1e-5f);
}

// ---------------- pooled partial sums: part[ch][b][dm] ----------------
__global__ void k_pool(const float* __restrict__ t, const float* __restrict__ rinv,
                       float* __restrict__ part) {
  const int b = blockIdx.x, dmb = blockIdx.y, ch = blockIdx.z;
  const int dm = dmb * 64 + threadIdx.x;
  const int lbeg = ch * (SL / 32);
  float s = 0.f;
  for (int l = lbeg; l < lbeg + SL / 32; ++l)
    s = fmaf(t[((size_t)b * SL + l) * DM + dm], rinv[b * SL + l], s);
  part[((size_t)ch * NB + b) * DM + dm] = s;
}

// ---------------- head: out[b][cls] ----------------
__global__ void k_head(const float* __restrict__ part, const float* __restrict__ norm_w,
                       const float* __restrict__ hw, const float* __restrict__ hb,
                       float* __restrict__ out) {
  const int b = blockIdx.x;
  const int tid = threadIdx.x;  // 64
  __shared__ float pv[DM];
  for (int k = tid; k < DM; k += 64) {
    float s = 0.f;
#pragma unroll
    for (int c = 0; c < 32; ++c) s += part[((size_t)c * NB + b) * DM + k];
    pv[k] = s * norm_w[k] * (1.f / SL);
  }
  __syncthreads();
  const int cls = blockIdx.y * 64 + tid;
  if (cls < NCLS) {
    const float* wr = hw + (size_t)cls * DM;
    float acc = hb[cls];
#pragma unroll 4
    for (int k = 0; k < DM; k += 4) {
      const float4 w4 = *(const float4*)&wr[k];
      acc = fmaf(pv[k], w4.x, acc);
      acc = fmaf(pv[k + 1], w4.y, acc);
      acc = fmaf(pv[k + 2], w4.z, acc);
      acc = fmaf(pv[k + 3], w4.w, acc);
    }
    out[(size_t)b * NCLS + cls] = acc;
  }
}

extern "C" void kernel_launch(void* const* d_in, const int* in_sizes, int n_in,
                              void* d_out, int out_size, void* d_ws, size_t ws_size,
                              hipStream_t stream) {
  (void)in_sizes; (void)n_in; (void)out_size; (void)ws_size;
  const float* x = (const float*)d_in[0];
  const float* patch_w = (const float*)d_in[1];
  const float* patch_b = (const float*)d_in[2];
  const float* in_proj_w = (const float*)d_in[3];
  const float* conv_w = (const float*)d_in[4];
  const float* conv_b = (const float*)d_in[5];
  const float* x_proj_w = (const float*)d_in[6];
  const float* dt_proj_w = (const float*)d_in[7];
  const float* dt_proj_b = (const float*)d_in[8];
  const float* A_log = (const float*)d_in[9];
  const float* Dp = (const float*)d_in[10];
  const float* out_proj_w = (const float*)d_in[11];
  const float* norm_w = (const float*)d_in[12];
  const float* head_w = (const float*)d_in[13];
  const float* head_b = (const float*)d_in[14];

  float* ws = (float*)d_ws;
  size_t o = 0;
  float* t = ws + o;    o += (size_t)NB * SL * DM;
  float* xcT = ws + o;  o += (size_t)NB * DI * SL;
  float* res = ws + o;  o += (size_t)NB * SL * DI;
  float* uT = ws + o;   o += (size_t)NB * DI * SL;
  float* dbl = ws + o;  o += (size_t)NB * SL * XPN;
  float* dltT = ws + o; o += (size_t)NB * DI * SL;
  float* y = ws + o;    o += (size_t)NB * SL * DI;
  float* rinv = ws + o; o += (size_t)NB * SL;
  float* part = ws + o; o += (size_t)32 * NB * DM;

  k_patch<<<NB * SL, 128, 0, stream>>>(x, patch_w, patch_b, t);

  for (int i = 0; i < NLAYER; ++i) {
    // in_proj: [R,384] x [1536,384]^T -> xcT (transposed) + res
    k_gemm<1, false, false, 64><<<dim3(196, 24), 256, 0, stream>>>(
        t, in_proj_w + (size_t)i * 2 * DI * DM, nullptr, xcT, res, DM, DM);
    // depthwise causal conv + silu -> uT
    k_conv<<<(NB * DI * SL) / 256, 256, 0, stream>>>(
        xcT, conv_w + (size_t)i * DI * 4, conv_b + (size_t)i * DI, uT);
    // x_proj: [R,768] x [56,768]^T -> dbl   (A read transposed from uT)
    k_gemm<0, true, false, XPN><<<dim3(196, 1), 256, 0, stream>>>(
        uT, x_proj_w + (size_t)i * XPN * DI, nullptr, dbl, nullptr, DI, 0);
    // dt_proj: [R,24] x [768,24]^T + b -> softplus -> deltaT (transposed)
    k_gemm<2, false, true, 64><<<dim3(196, 12), 256, 0, stream>>>(
        dbl, dt_proj_w + (size_t)i * DI * DR, dt_proj_b + (size_t)i * DI, dltT,
        nullptr, DR, XPN);
    // selective scan + gate -> y
    k_scan<<<(NB * DI) / 16, 256, 0, stream>>>(
        dltT, uT, dbl, res, A_log + (size_t)i * DI * DSN, Dp + (size_t)i * DI, y);
    // out_proj: [R,768] x [384,768]^T, accumulate into t
    k_gemm<3, false, false, 64><<<dim3(196, 6), 256, 0, stream>>>(
        y, out_proj_w + (size_t)i * DM * DI, nullptr, t, nullptr, DI, DI);
  }

  k_rinv<<<NB * SL, 64, 0, stream>>>(t, rinv);
  k_pool<<<dim3(NB, DM / 64, 32), 64, 0, stream>>>(t, rinv, part);
  k_head<<<dim3(NB, 16), 64, 0, stream>>>(part, norm_w, head_w, head_b, (float*)d_out);
}

// Round 2
// 3173.199 us; speedup vs baseline: 2.6167x; 2.6167x over previous
//
#include <hip/hip_runtime.h>
#include <math.h>

// CausalVisionMamba — fp32, chunked selective scan (round 2).
// B=4, L=3136(56x56), D_MODEL=384, D_INNER=768, D_STATE=16, DT_RANK=24, 4 layers.

namespace {
constexpr int NB = 4;
constexpr int SL = 3136;   // sequence length 56*56
constexpr int DM = 384;    // d_model
constexpr int DI = 768;    // d_inner
constexpr int DSN = 16;    // d_state
constexpr int DR = 24;     // dt_rank
constexpr int NLAYER = 4;
constexpr int NCLS = 1000;
constexpr int XPN = DR + 2 * DSN;  // 56
constexpr int CH = 14;             // scan chunks
constexpr int CLEN = SL / CH;      // 224 steps per chunk (multiple of 8)
constexpr int NCHAIN = NB * DI;    // 3072
constexpr int NG = NCHAIN * CH;    // chunk-groups
}

__device__ __forceinline__ float siluf(float x) { return x / (1.f + expf(-x)); }
__device__ __forceinline__ float softplusf(float x) {
  return fmaxf(x, 0.f) + log1pf(expf(-fabsf(x)));
}

// ---------------- patch embed: t[b][l][dm] ----------------
__global__ void k_patch(const float* __restrict__ x, const float* __restrict__ w,
                        const float* __restrict__ bias, float* __restrict__ t) {
  const int blk = blockIdx.x;  // b*SL + l
  const int b = blk / SL, l = blk % SL;
  const int hh = l / 56, ww = l % 56;
  __shared__ float patch[48];
  const int tid = threadIdx.x;
  if (tid < 48) {
    const int c = tid / 16, kh = (tid % 16) / 4, kw = tid % 4;
    patch[tid] = x[((size_t)(b * 3 + c) * 224 + (hh * 4 + kh)) * 224 + (ww * 4 + kw)];
  }
  __syncthreads();
  for (int dm = tid; dm < DM; dm += 128) {
    const float* wr = w + (size_t)dm * 48;
    float acc = bias[dm];
#pragma unroll
    for (int p = 0; p < 48; ++p) acc = fmaf(patch[p], wr[p], acc);
    t[((size_t)b * SL + l) * DM + dm] = acc;
  }
}

// ---------------- generic tiled fp32 GEMM: C = A[M,K] * W[N,K]^T ----------------
// EPI 0: plain write to out[m*56 + n], n < NCAP (x_proj -> dbl)
// EPI 1: in_proj split: n<DI -> transposed out[b][n][l] (xcT); n>=DI -> out2[m][n-DI] (res)
// EPI 2: dt_proj: softplus(acc + bias[n]) -> transposed out[b][n][l] (deltaT)
// EPI 3: out_proj: out[m*DM + n] += acc  (residual accumulate into t)
// ATRANS: A[m][k] = A[(b*K + k)*SL + l]  (A stored [B][K][L], for x_proj reading uT)
template <int EPI, bool ATRANS, bool KTAIL, int NCAP>
__global__ __launch_bounds__(256) void k_gemm(
    const float* __restrict__ A, const float* __restrict__ W,
    const float* __restrict__ bias, float* __restrict__ out,
    float* __restrict__ out2, int K, int lda) {
  __shared__ float sm[4352];  // staging: As[16][68] + Ws[16][68]; epilogue: Cs[64][68]
  const int tid = threadIdx.x;
  const int m0 = blockIdx.x * 64;
  const int n0 = blockIdx.y * 64;
  const int b = m0 / SL, l0 = m0 % SL;
  const int tm = tid >> 4, tn = tid & 15;
  float acc[4][4] = {};
  float* As = sm;
  float* Ws = sm + 16 * 68;

  const int nk = (K + 15) / 16;
  for (int kt = 0; kt < nk; ++kt) {
    const int k0 = kt * 16;
    if (ATRANS) {
      const int kk = tid >> 4;
      const int lq = (tid & 15) * 4;
      const float4 v = *(const float4*)&A[((size_t)(b * K + k0 + kk)) * SL + l0 + lq];
      *(float4*)&As[kk * 68 + lq] = v;
    } else {
      const int row = tid >> 2;
      const int kq = (tid & 3) * 4;
      const int kb = k0 + kq;
      float4 v = make_float4(0.f, 0.f, 0.f, 0.f);
      if (!KTAIL || kb < K) v = *(const float4*)&A[(size_t)(m0 + row) * lda + kb];
      As[(kq + 0) * 68 + row] = v.x;
      As[(kq + 1) * 68 + row] = v.y;
      As[(kq + 2) * 68 + row] = v.z;
      As[(kq + 3) * 68 + row] = v.w;
    }
    {
      const int row = tid >> 2;
      const int kq = (tid & 3) * 4;
      const int kb = k0 + kq;
      float4 v = make_float4(0.f, 0.f, 0.f, 0.f);
      const bool nok = (NCAP % 64 == 0) || (n0 + row < NCAP);
      if (nok && (!KTAIL || kb < K)) v = *(const float4*)&W[(size_t)(n0 + row) * K + kb];
      Ws[(kq + 0) * 68 + row] = v.x;
      Ws[(kq + 1) * 68 + row] = v.y;
      Ws[(kq + 2) * 68 + row] = v.z;
      Ws[(kq + 3) * 68 + row] = v.w;
    }
    __syncthreads();
#pragma unroll
    for (int kk = 0; kk < 16; ++kk) {
      const float4 av = *(const float4*)&As[kk * 68 + 4 * tm];
      const float4 wv = *(const float4*)&Ws[kk * 68 + 4 * tn];
      const float ax[4] = {av.x, av.y, av.z, av.w};
      const float wx[4] = {wv.x, wv.y, wv.z, wv.w};
#pragma unroll
      for (int i = 0; i < 4; ++i)
#pragma unroll
        for (int j = 0; j < 4; ++j) acc[i][j] = fmaf(ax[i], wx[j], acc[i][j]);
    }
    __syncthreads();
  }

  if (EPI == 0) {
#pragma unroll
    for (int i = 0; i < 4; ++i) {
      const size_t ro = (size_t)(m0 + 4 * tm + i) * 56;
#pragma unroll
      for (int j = 0; j < 4; ++j) {
        const int nn = n0 + 4 * tn + j;
        if (nn < NCAP) out[ro + nn] = acc[i][j];
      }
    }
  } else if (EPI == 3) {
#pragma unroll
    for (int i = 0; i < 4; ++i) {
      const size_t o = (size_t)(m0 + 4 * tm + i) * DM + n0 + 4 * tn;
      float4 c = *(float4*)&out[o];
      c.x += acc[i][0];
      c.y += acc[i][1];
      c.z += acc[i][2];
      c.w += acc[i][3];
      *(float4*)&out[o] = c;
    }
  } else {
    if (EPI == 1 && n0 >= DI) {
#pragma unroll
      for (int i = 0; i < 4; ++i) {
        const float4 c = make_float4(acc[i][0], acc[i][1], acc[i][2], acc[i][3]);
        *(float4*)&out2[(size_t)(m0 + 4 * tm + i) * DI + (n0 - DI) + 4 * tn] = c;
      }
    } else {
      // transpose epilogue through LDS -> out[b][n][l] coalesced along l
#pragma unroll
      for (int j = 0; j < 4; ++j) {
        const int nn = 4 * tn + j;
#pragma unroll
        for (int i = 0; i < 4; ++i) {
          float v = acc[i][j];
          if (EPI == 2) v = softplusf(v + bias[n0 + nn]);
          sm[nn * 68 + 4 * tm + i] = v;
        }
      }
      __syncthreads();
      const int row = tid >> 2;           // local n (0..63)
      const int seg = (tid & 3) * 16;     // l segment
      float* dst = out + ((size_t)(b * DI + n0 + row)) * SL + l0 + seg;
#pragma unroll
      for (int q = 0; q < 4; ++q) {
        *(float4*)&dst[q * 4] = *(const float4*)&sm[row * 68 + seg + q * 4];
      }
    }
  }
}

// ---------------- depthwise causal conv1d + bias + silu: uT[b][d][l] ----------------
__global__ void k_conv(const float* __restrict__ xcT, const float* __restrict__ cw,
                       const float* __restrict__ cb, float* __restrict__ uT) {
  const size_t idx = (size_t)blockIdx.x * 256 + threadIdx.x;
  const int l = (int)(idx % SL);
  const int bd = (int)(idx / SL);
  const int d = bd % DI;
  const float* row = xcT + (size_t)bd * SL;
  const float4 w = *(const float4*)&cw[d * 4];
  float acc = cb[d] + w.w * row[l];
  if (l >= 1) acc = fmaf(w.z, row[l - 1], acc);
  if (l >= 2) acc = fmaf(w.y, row[l - 2], acc);
  if (l >= 3) acc = fmaf(w.x, row[l - 3], acc);
  uT[idx] = siluf(acc);
}

// ---------------- chunked selective scan ----------------
// Pass 1: per (chain, chunk, n): local scan from h=0 -> hend; Aprod=exp2(a2*sum(delta)).
// group g (16 lanes) handles chunk-group gidx = blockIdx.x*16+g; chain=gidx/CH, c=gidx%CH.
__global__ __launch_bounds__(256) void k_scan1(
    const float* __restrict__ deltaT, const float* __restrict__ uT,
    const float* __restrict__ dbl, const float* __restrict__ A_log,
    float* __restrict__ hend, float* __restrict__ aprod) {
  const int tid = threadIdx.x;
  const int n = tid & 15, g = tid >> 4;
  const int gidx = blockIdx.x * 16 + g;
  const int chain = gidx / CH, c = gidx % CH;
  const int b = chain / DI, d = chain % DI;
  const float a2 = -expf(A_log[d * DSN + n]) * 1.44269504088896341f;
  const int base = c * CLEN;
  const float* drow = deltaT + (size_t)chain * SL + base;
  const float* urow = uT + (size_t)chain * SL + base;
  const float* dblb = dbl + (size_t)b * SL * XPN + (size_t)base * XPN;
  float h = 0.f, dsum = 0.f;
  for (int l0 = 0; l0 < CLEN; l0 += 8) {
    const float4 dv0 = *(const float4*)&drow[l0];
    const float4 dv1 = *(const float4*)&drow[l0 + 4];
    const float4 uv0 = *(const float4*)&urow[l0];
    const float4 uv1 = *(const float4*)&urow[l0 + 4];
    float Bv[8];
#pragma unroll
    for (int j = 0; j < 8; ++j) Bv[j] = dblb[(size_t)(l0 + j) * XPN + DR + n];
    const float dvv[8] = {dv0.x, dv0.y, dv0.z, dv0.w, dv1.x, dv1.y, dv1.z, dv1.w};
    const float uvv[8] = {uv0.x, uv0.y, uv0.z, uv0.w, uv1.x, uv1.y, uv1.z, uv1.w};
#pragma unroll
    for (int j = 0; j < 8; ++j) {
      const float dl = dvv[j];
      const float da = exp2f(dl * a2);
      h = fmaf(da, h, dl * uvv[j] * Bv[j]);
      dsum += dl;
    }
  }
  hend[(size_t)gidx * 16 + n] = h;
  aprod[(size_t)gidx * 16 + n] = exp2f(a2 * dsum);
}

// Mid: per (chain, n): scan over CH chunk states -> hinit per chunk.
__global__ __launch_bounds__(256) void k_scanmid(
    const float* __restrict__ hend, const float* __restrict__ aprod,
    float* __restrict__ hinit) {
  const int gid = blockIdx.x * 256 + threadIdx.x;  // chain*16 + n
  const int chain = gid >> 4, n = gid & 15;
  float H = 0.f;
  for (int c = 0; c < CH; ++c) {
    const size_t o = ((size_t)chain * CH + c) * 16 + n;
    hinit[o] = H;
    H = fmaf(aprod[o], H, hend[o]);
  }
}

// Pass 2: re-scan each chunk from hinit; y = (h·C + u*Dp) * silu(res).
__global__ __launch_bounds__(256) void k_scan2(
    const float* __restrict__ deltaT, const float* __restrict__ uT,
    const float* __restrict__ dbl, const float* __restrict__ res,
    const float* __restrict__ A_log, const float* __restrict__ Dp,
    const float* __restrict__ hinit, float* __restrict__ y) {
  const int tid = threadIdx.x;
  const int n = tid & 15, g = tid >> 4;
  const int gidx = blockIdx.x * 16 + g;
  const int chain = gidx / CH, c = gidx % CH;
  const int b = chain / DI, d = chain % DI;
  const float a2 = -expf(A_log[d * DSN + n]) * 1.44269504088896341f;
  const float dp = Dp[d];
  const int base = c * CLEN;
  const float* drow = deltaT + (size_t)chain * SL + base;
  const float* urow = uT + (size_t)chain * SL + base;
  const float* dblb = dbl + (size_t)b * SL * XPN + (size_t)base * XPN;
  const float* resb = res + ((size_t)b * SL + base) * DI + d;
  float* yb = y + ((size_t)b * SL + base) * DI + d;
  float h = hinit[(size_t)gidx * 16 + n];
  for (int l0 = 0; l0 < CLEN; l0 += 8) {
    const float4 dv0 = *(const float4*)&drow[l0];
    const float4 dv1 = *(const float4*)&drow[l0 + 4];
    const float4 uv0 = *(const float4*)&urow[l0];
    const float4 uv1 = *(const float4*)&urow[l0 + 4];
    float Bv[8], Cv[8];
#pragma unroll
    for (int j = 0; j < 8; ++j) {
      Bv[j] = dblb[(size_t)(l0 + j) * XPN + DR + n];
      Cv[j] = dblb[(size_t)(l0 + j) * XPN + DR + DSN + n];
    }
    const float dvv[8] = {dv0.x, dv0.y, dv0.z, dv0.w, dv1.x, dv1.y, dv1.z, dv1.w};
    const float uvv[8] = {uv0.x, uv0.y, uv0.z, uv0.w, uv1.x, uv1.y, uv1.z, uv1.w};
    float p[8];
#pragma unroll
    for (int j = 0; j < 8; ++j) {
      const float dl = dvv[j];
      const float da = exp2f(dl * a2);
      h = fmaf(da, h, dl * uvv[j] * Bv[j]);
      p[j] = h * Cv[j];
    }
    // 8 independent butterfly trees (4 rounds), latencies overlap
#pragma unroll
    for (int j = 0; j < 8; ++j) p[j] += __shfl_xor(p[j], 1);
#pragma unroll
    for (int j = 0; j < 8; ++j) p[j] += __shfl_xor(p[j], 2);
#pragma unroll
    for (int j = 0; j < 8; ++j) p[j] += __shfl_xor(p[j], 4);
#pragma unroll
    for (int j = 0; j < 8; ++j) p[j] += __shfl_xor(p[j], 8);
    // lane j (j<8) writes step j; select p[j]/u[j] without runtime reg-indexing
    float myp = p[0], myu = uvv[0];
#pragma unroll
    for (int j = 1; j < 8; ++j) {
      const bool e = (n == j);
      myp = e ? p[j] : myp;
      myu = e ? uvv[j] : myu;
    }
    if (n < 8) {
      const float r = resb[(size_t)(l0 + n) * DI];
      yb[(size_t)(l0 + n) * DI] = (myp + myu * dp) * siluf(r);
    }
  }
}

// ---------------- RMS denom: rinv[b*SL+l] = 1/sqrt(mean(t^2)+eps) ----------------
__global__ void k_rinv(const float* __restrict__ t, float* __restrict__ rinv) {
  const int row = blockIdx.x;
  const float* tr = t + (size_t)row * DM;
  const int tid = threadIdx.x;  // 64
  float ss = 0.f;
#pragma unroll
  for (int k = 0; k < DM / 64; ++k) {
    const float v = tr[tid + k * 64];
    ss = fmaf(v, v, ss);
  }
  ss += __shfl_xor(ss, 1);
  ss += __shfl_xor(ss, 2);
  ss += __shfl_xor(ss, 4);
  ss += __shfl_xor(ss, 8);
  ss += __shfl_xor(ss, 16);
  ss += __shfl_xor(ss, 32);
  if (tid == 0) rinv[row] = 1.f / sqrtf(ss / DM + 1e-5f);
}

// ---------------- pooled partial sums: part[ch][b][dm] ----------------
__global__ void k_pool(const float* __restrict__ t, const float* __restrict__ rinv,
                       float* __restrict__ part) {
  const int b = blockIdx.x, dmb = blockIdx.y, ch = blockIdx.z;
  const int dm = dmb * 64 + threadIdx.x;
  const int lbeg = ch * (SL / 32);
  float s = 0.f;
  for (int l = lbeg; l < lbeg + SL / 32; ++l)
    s = fmaf(t[((size_t)b * SL + l) * DM + dm], rinv[b * SL + l], s);
  part[((size_t)ch * NB + b) * DM + dm] = s;
}

// ---------------- head: out[b][cls] ----------------
__global__ void k_head(const float* __restrict__ part, const float* __restrict__ norm_w,
                       const float* __restrict__ hw, const float* __restrict__ hb,
                       float* __restrict__ out) {
  const int b = blockIdx.x;
  const int tid = threadIdx.x;  // 64
  __shared__ float pv[DM];
  for (int k = tid; k < DM; k += 64) {
    float s = 0.f;
#pragma unroll
    for (int c = 0; c < 32; ++c) s += part[((size_t)c * NB + b) * DM + k];
    pv[k] = s * norm_w[k] * (1.f / SL);
  }
  __syncthreads();
  const int cls = blockIdx.y * 64 + tid;
  if (cls < NCLS) {
    const float* wr = hw + (size_t)cls * DM;
    float acc = hb[cls];
#pragma unroll 4
    for (int k = 0; k < DM; k += 4) {
      const float4 w4 = *(const float4*)&wr[k];
      acc = fmaf(pv[k], w4.x, acc);
      acc = fmaf(pv[k + 1], w4.y, acc);
      acc = fmaf(pv[k + 2], w4.z, acc);
      acc = fmaf(pv[k + 3], w4.w, acc);
    }
    out[(size_t)b * NCLS + cls] = acc;
  }
}

extern "C" void kernel_launch(void* const* d_in, const int* in_sizes, int n_in,
                              void* d_out, int out_size, void* d_ws, size_t ws_size,
                              hipStream_t stream) {
  (void)in_sizes; (void)n_in; (void)out_size; (void)ws_size;
  const float* x = (const float*)d_in[0];
  const float* patch_w = (const float*)d_in[1];
  const float* patch_b = (const float*)d_in[2];
  const float* in_proj_w = (const float*)d_in[3];
  const float* conv_w = (const float*)d_in[4];
  const float* conv_b = (const float*)d_in[5];
  const float* x_proj_w = (const float*)d_in[6];
  const float* dt_proj_w = (const float*)d_in[7];
  const float* dt_proj_b = (const float*)d_in[8];
  const float* A_log = (const float*)d_in[9];
  const float* Dp = (const float*)d_in[10];
  const float* out_proj_w = (const float*)d_in[11];
  const float* norm_w = (const float*)d_in[12];
  const float* head_w = (const float*)d_in[13];
  const float* head_b = (const float*)d_in[14];

  float* ws = (float*)d_ws;
  size_t o = 0;
  float* t = ws + o;    o += (size_t)NB * SL * DM;
  float* xcT = ws + o;  o += (size_t)NB * DI * SL;
  float* res = ws + o;  o += (size_t)NB * SL * DI;
  float* uT = ws + o;   o += (size_t)NB * DI * SL;
  float* dbl = ws + o;  o += (size_t)NB * SL * XPN;
  float* dltT = ws + o; o += (size_t)NB * DI * SL;
  float* y = ws + o;    o += (size_t)NB * SL * DI;
  float* rinv = ws + o; o += (size_t)NB * SL;
  float* part = ws + o; o += (size_t)32 * NB * DM;
  float* hend = ws + o;  o += (size_t)NG * 16;
  float* aprod = ws + o; o += (size_t)NG * 16;
  float* hinit = ws + o; o += (size_t)NG * 16;

  k_patch<<<NB * SL, 128, 0, stream>>>(x, patch_w, patch_b, t);

  for (int i = 0; i < NLAYER; ++i) {
    // in_proj: [R,384] x [1536,384]^T -> xcT (transposed) + res
    k_gemm<1, false, false, 64><<<dim3(196, 24), 256, 0, stream>>>(
        t, in_proj_w + (size_t)i * 2 * DI * DM, nullptr, xcT, res, DM, DM);
    // depthwise causal conv + silu -> uT
    k_conv<<<(NB * DI * SL) / 256, 256, 0, stream>>>(
        xcT, conv_w + (size_t)i * DI * 4, conv_b + (size_t)i * DI, uT);
    // x_proj: [R,768] x [56,768]^T -> dbl   (A read transposed from uT)
    k_gemm<0, true, false, XPN><<<dim3(196, 1), 256, 0, stream>>>(
        uT, x_proj_w + (size_t)i * XPN * DI, nullptr, dbl, nullptr, DI, 0);
    // dt_proj: [R,24] x [768,24]^T + b -> softplus -> deltaT (transposed)
    k_gemm<2, false, true, 64><<<dim3(196, 12), 256, 0, stream>>>(
        dbl, dt_proj_w + (size_t)i * DI * DR, dt_proj_b + (size_t)i * DI, dltT,
        nullptr, DR, XPN);
    // chunked selective scan + gate -> y
    k_scan1<<<NG / 16, 256, 0, stream>>>(
        dltT, uT, dbl, A_log + (size_t)i * DI * DSN, hend, aprod);
    k_scanmid<<<(NCHAIN * 16) / 256, 256, 0, stream>>>(hend, aprod, hinit);
    k_scan2<<<NG / 16, 256, 0, stream>>>(
        dltT, uT, dbl, res, A_log + (size_t)i * DI * DSN, Dp + (size_t)i * DI,
        hinit, y);
    // out_proj: [R,768] x [384,768]^T, accumulate into t
    k_gemm<3, false, false, 64><<<dim3(196, 6), 256, 0, stream>>>(
        y, out_proj_w + (size_t)i * DM * DI, nullptr, t, nullptr, DI, DI);
  }

  k_rinv<<<NB * SL, 64, 0, stream>>>(t, rinv);
  k_pool<<<dim3(NB, DM / 64, 32), 64, 0, stream>>>(t, rinv, part);
  k_head<<<dim3(NB, 16), 64, 0, stream>>>(part, norm_w, head_w, head_b, (float*)d_out);
}

// Round 3
// 2713.136 us; speedup vs baseline: 3.0604x; 1.1696x over previous
//
#include <hip/hip_runtime.h>
#include <math.h>

// CausalVisionMamba — fp32, chunked scan + transposed res/y layout (round 3).
// B=4, L=3136(56x56), D_MODEL=384, D_INNER=768, D_STATE=16, DT_RANK=24, 4 layers.

namespace {
constexpr int NB = 4;
constexpr int SL = 3136;   // sequence length 56*56
constexpr int DM = 384;    // d_model
constexpr int DI = 768;    // d_inner
constexpr int DSN = 16;    // d_state
constexpr int DR = 24;     // dt_rank
constexpr int NLAYER = 4;
constexpr int NCLS = 1000;
constexpr int XPN = DR + 2 * DSN;  // 56
constexpr int CH = 14;             // scan chunks
constexpr int CLEN = SL / CH;      // 224 steps per chunk (multiple of 8)
constexpr int NCHAIN = NB * DI;    // 3072
constexpr int NG = NCHAIN * CH;    // chunk-groups
}

__device__ __forceinline__ float siluf(float x) { return x / (1.f + expf(-x)); }
__device__ __forceinline__ float softplusf(float x) {
  return fmaxf(x, 0.f) + log1pf(expf(-fabsf(x)));
}

// ---------------- patch embed: t[b][l][dm] ----------------
__global__ void k_patch(const float* __restrict__ x, const float* __restrict__ w,
                        const float* __restrict__ bias, float* __restrict__ t) {
  const int blk = blockIdx.x;  // b*SL + l
  const int b = blk / SL, l = blk % SL;
  const int hh = l / 56, ww = l % 56;
  __shared__ float patch[48];
  const int tid = threadIdx.x;
  if (tid < 48) {
    const int c = tid / 16, kh = (tid % 16) / 4, kw = tid % 4;
    patch[tid] = x[((size_t)(b * 3 + c) * 224 + (hh * 4 + kh)) * 224 + (ww * 4 + kw)];
  }
  __syncthreads();
  for (int dm = tid; dm < DM; dm += 128) {
    const float* wr = w + (size_t)dm * 48;
    float acc = bias[dm];
#pragma unroll
    for (int p = 0; p < 48; ++p) acc = fmaf(patch[p], wr[p], acc);
    t[((size_t)b * SL + l) * DM + dm] = acc;
  }
}

// ---------------- generic tiled fp32 GEMM: C = A[M,K] * W[N,K]^T ----------------
// EPI 0: plain write to out[m*56 + n], n < NCAP (x_proj -> dbl)
// EPI 1: in_proj: n<DI -> transposed out[b][n][l] (xcT); n>=DI -> transposed out2 (resT)
// EPI 2: dt_proj: softplus(acc + bias[n]) -> transposed out[b][n][l] (deltaT)
// EPI 3: out_proj: out[m*DM + n] += acc  (residual accumulate into t)
// ATRANS: A[m][k] = A[(b*K + k)*SL + l]  (A stored [B][K][L]: uT / yT)
template <int EPI, bool ATRANS, bool KTAIL, int NCAP>
__global__ __launch_bounds__(256) void k_gemm(
    const float* __restrict__ A, const float* __restrict__ W,
    const float* __restrict__ bias, float* __restrict__ out,
    float* __restrict__ out2, int K, int lda) {
  __shared__ float sm[4352];  // staging: As[16][68] + Ws[16][68]; epilogue: Cs[64][68]
  const int tid = threadIdx.x;
  const int m0 = blockIdx.x * 64;
  const int n0 = blockIdx.y * 64;
  const int b = m0 / SL, l0 = m0 % SL;
  const int tm = tid >> 4, tn = tid & 15;
  float acc[4][4] = {};
  float* As = sm;
  float* Ws = sm + 16 * 68;

  const int nk = (K + 15) / 16;
  for (int kt = 0; kt < nk; ++kt) {
    const int k0 = kt * 16;
    if (ATRANS) {
      const int kk = tid >> 4;
      const int lq = (tid & 15) * 4;
      const float4 v = *(const float4*)&A[((size_t)(b * K + k0 + kk)) * SL + l0 + lq];
      *(float4*)&As[kk * 68 + lq] = v;
    } else {
      const int row = tid >> 2;
      const int kq = (tid & 3) * 4;
      const int kb = k0 + kq;
      float4 v = make_float4(0.f, 0.f, 0.f, 0.f);
      if (!KTAIL || kb < K) v = *(const float4*)&A[(size_t)(m0 + row) * lda + kb];
      As[(kq + 0) * 68 + row] = v.x;
      As[(kq + 1) * 68 + row] = v.y;
      As[(kq + 2) * 68 + row] = v.z;
      As[(kq + 3) * 68 + row] = v.w;
    }
    {
      const int row = tid >> 2;
      const int kq = (tid & 3) * 4;
      const int kb = k0 + kq;
      float4 v = make_float4(0.f, 0.f, 0.f, 0.f);
      const bool nok = (NCAP % 64 == 0) || (n0 + row < NCAP);
      if (nok && (!KTAIL || kb < K)) v = *(const float4*)&W[(size_t)(n0 + row) * K + kb];
      Ws[(kq + 0) * 68 + row] = v.x;
      Ws[(kq + 1) * 68 + row] = v.y;
      Ws[(kq + 2) * 68 + row] = v.z;
      Ws[(kq + 3) * 68 + row] = v.w;
    }
    __syncthreads();
#pragma unroll
    for (int kk = 0; kk < 16; ++kk) {
      const float4 av = *(const float4*)&As[kk * 68 + 4 * tm];
      const float4 wv = *(const float4*)&Ws[kk * 68 + 4 * tn];
      const float ax[4] = {av.x, av.y, av.z, av.w};
      const float wx[4] = {wv.x, wv.y, wv.z, wv.w};
#pragma unroll
      for (int i = 0; i < 4; ++i)
#pragma unroll
        for (int j = 0; j < 4; ++j) acc[i][j] = fmaf(ax[i], wx[j], acc[i][j]);
    }
    __syncthreads();
  }

  if (EPI == 0) {
#pragma unroll
    for (int i = 0; i < 4; ++i) {
      const size_t ro = (size_t)(m0 + 4 * tm + i) * 56;
#pragma unroll
      for (int j = 0; j < 4; ++j) {
        const int nn = n0 + 4 * tn + j;
        if (nn < NCAP) out[ro + nn] = acc[i][j];
      }
    }
  } else if (EPI == 3) {
#pragma unroll
    for (int i = 0; i < 4; ++i) {
      const size_t o = (size_t)(m0 + 4 * tm + i) * DM + n0 + 4 * tn;
      float4 c = *(float4*)&out[o];
      c.x += acc[i][0];
      c.y += acc[i][1];
      c.z += acc[i][2];
      c.w += acc[i][3];
      *(float4*)&out[o] = c;
    }
  } else {
    // transpose epilogue through LDS -> [b][n][l], coalesced along l
#pragma unroll
    for (int j = 0; j < 4; ++j) {
      const int nn = 4 * tn + j;
#pragma unroll
      for (int i = 0; i < 4; ++i) {
        float v = acc[i][j];
        if (EPI == 2) v = softplusf(v + bias[n0 + nn]);
        sm[nn * 68 + 4 * tm + i] = v;
      }
    }
    __syncthreads();
    const int row = tid >> 2;           // local n (0..63)
    const int seg = (tid & 3) * 16;     // l segment
    const float* src = &sm[row * 68 + seg];
    float* dstbase = out;
    int nloc = n0;
    if (EPI == 1 && n0 >= DI) { dstbase = out2; nloc = n0 - DI; }
    float* dst = dstbase + ((size_t)(b * DI + nloc + row)) * SL + l0 + seg;
#pragma unroll
    for (int q = 0; q < 4; ++q) {
      *(float4*)&dst[q * 4] = *(const float4*)&src[q * 4];
    }
  }
}

// ---------------- depthwise causal conv1d + bias + silu: uT[b][d][l] ----------------
__global__ void k_conv(const float* __restrict__ xcT, const float* __restrict__ cw,
                       const float* __restrict__ cb, float* __restrict__ uT) {
  const size_t idx = (size_t)blockIdx.x * 256 + threadIdx.x;
  const int l = (int)(idx % SL);
  const int bd = (int)(idx / SL);
  const int d = bd % DI;
  const float* row = xcT + (size_t)bd * SL;
  const float4 w = *(const float4*)&cw[d * 4];
  float acc = cb[d] + w.w * row[l];
  if (l >= 1) acc = fmaf(w.z, row[l - 1], acc);
  if (l >= 2) acc = fmaf(w.y, row[l - 2], acc);
  if (l >= 3) acc = fmaf(w.x, row[l - 3], acc);
  uT[idx] = siluf(acc);
}

// ---------------- chunked selective scan ----------------
// Pass 1: per (chain, chunk, n): local scan from h=0 -> hend; Aprod=exp2(a2*sum(delta)).
__global__ __launch_bounds__(256) void k_scan1(
    const float* __restrict__ deltaT, const float* __restrict__ uT,
    const float* __restrict__ dbl, const float* __restrict__ A_log,
    float* __restrict__ hend, float* __restrict__ aprod) {
  const int tid = threadIdx.x;
  const int n = tid & 15, g = tid >> 4;
  const int gidx = blockIdx.x * 16 + g;
  const int chain = gidx / CH, c = gidx % CH;
  const int b = chain / DI, d = chain % DI;
  const float a2 = -expf(A_log[d * DSN + n]) * 1.44269504088896341f;
  const int base = c * CLEN;
  const float* drow = deltaT + (size_t)chain * SL + base;
  const float* urow = uT + (size_t)chain * SL + base;
  const float* dblb = dbl + (size_t)b * SL * XPN + (size_t)base * XPN;
  float h = 0.f, dsum = 0.f;
  for (int l0 = 0; l0 < CLEN; l0 += 8) {
    const float4 dv0 = *(const float4*)&drow[l0];
    const float4 dv1 = *(const float4*)&drow[l0 + 4];
    const float4 uv0 = *(const float4*)&urow[l0];
    const float4 uv1 = *(const float4*)&urow[l0 + 4];
    float Bv[8];
#pragma unroll
    for (int j = 0; j < 8; ++j) Bv[j] = dblb[(size_t)(l0 + j) * XPN + DR + n];
    const float dvv[8] = {dv0.x, dv0.y, dv0.z, dv0.w, dv1.x, dv1.y, dv1.z, dv1.w};
    const float uvv[8] = {uv0.x, uv0.y, uv0.z, uv0.w, uv1.x, uv1.y, uv1.z, uv1.w};
#pragma unroll
    for (int j = 0; j < 8; ++j) {
      const float dl = dvv[j];
      const float da = exp2f(dl * a2);
      h = fmaf(da, h, dl * uvv[j] * Bv[j]);
      dsum += dl;
    }
  }
  hend[(size_t)gidx * 16 + n] = h;
  aprod[(size_t)gidx * 16 + n] = exp2f(a2 * dsum);
}

// Mid: per (chain, n): scan over CH chunk states -> hinit per chunk.
__global__ __launch_bounds__(256) void k_scanmid(
    const float* __restrict__ hend, const float* __restrict__ aprod,
    float* __restrict__ hinit) {
  const int gid = blockIdx.x * 256 + threadIdx.x;  // chain*16 + n
  const int chain = gid >> 4, n = gid & 15;
  float H = 0.f;
  for (int c = 0; c < CH; ++c) {
    const size_t o = ((size_t)chain * CH + c) * 16 + n;
    hinit[o] = H;
    H = fmaf(aprod[o], H, hend[o]);
  }
}

// Pass 2: re-scan each chunk from hinit; y = (h·C + u*Dp) * silu(res). resT/yT layout.
__global__ __launch_bounds__(256) void k_scan2(
    const float* __restrict__ deltaT, const float* __restrict__ uT,
    const float* __restrict__ dbl, const float* __restrict__ resT,
    const float* __restrict__ A_log, const float* __restrict__ Dp,
    const float* __restrict__ hinit, float* __restrict__ yT) {
  const int tid = threadIdx.x;
  const int n = tid & 15, g = tid >> 4;
  const int gidx = blockIdx.x * 16 + g;
  const int chain = gidx / CH, c = gidx % CH;
  const int b = chain / DI, d = chain % DI;
  const float a2 = -expf(A_log[d * DSN + n]) * 1.44269504088896341f;
  const float dp = Dp[d];
  const int base = c * CLEN;
  const float* drow = deltaT + (size_t)chain * SL + base;
  const float* urow = uT + (size_t)chain * SL + base;
  const float* dblb = dbl + (size_t)b * SL * XPN + (size_t)base * XPN;
  const float* resb = resT + (size_t)chain * SL + base;
  float* yb = yT + (size_t)chain * SL + base;
  float h = hinit[(size_t)gidx * 16 + n];
  for (int l0 = 0; l0 < CLEN; l0 += 8) {
    const float4 dv0 = *(const float4*)&drow[l0];
    const float4 dv1 = *(const float4*)&drow[l0 + 4];
    const float4 uv0 = *(const float4*)&urow[l0];
    const float4 uv1 = *(const float4*)&urow[l0 + 4];
    float Bv[8], Cv[8];
#pragma unroll
    for (int j = 0; j < 8; ++j) {
      Bv[j] = dblb[(size_t)(l0 + j) * XPN + DR + n];
      Cv[j] = dblb[(size_t)(l0 + j) * XPN + DR + DSN + n];
    }
    const float dvv[8] = {dv0.x, dv0.y, dv0.z, dv0.w, dv1.x, dv1.y, dv1.z, dv1.w};
    const float uvv[8] = {uv0.x, uv0.y, uv0.z, uv0.w, uv1.x, uv1.y, uv1.z, uv1.w};
    float p[8];
#pragma unroll
    for (int j = 0; j < 8; ++j) {
      const float dl = dvv[j];
      const float da = exp2f(dl * a2);
      h = fmaf(da, h, dl * uvv[j] * Bv[j]);
      p[j] = h * Cv[j];
    }
    // 8 independent butterfly trees (4 rounds), latencies overlap
#pragma unroll
    for (int j = 0; j < 8; ++j) p[j] += __shfl_xor(p[j], 1);
#pragma unroll
    for (int j = 0; j < 8; ++j) p[j] += __shfl_xor(p[j], 2);
#pragma unroll
    for (int j = 0; j < 8; ++j) p[j] += __shfl_xor(p[j], 4);
#pragma unroll
    for (int j = 0; j < 8; ++j) p[j] += __shfl_xor(p[j], 8);
    // lane j (j<8) writes step j; select p[j]/u[j] without runtime reg-indexing
    float myp = p[0], myu = uvv[0];
#pragma unroll
    for (int j = 1; j < 8; ++j) {
      const bool e = (n == j);
      myp = e ? p[j] : myp;
      myu = e ? uvv[j] : myu;
    }
    if (n < 8) {
      const float r = resb[l0 + n];
      yb[l0 + n] = (myp + myu * dp) * siluf(r);
    }
  }
}

// ---------------- RMS denom: rinv[b*SL+l] = 1/sqrt(mean(t^2)+eps) ----------------
__global__ void k_rinv(const float* __restrict__ t, float* __restrict__ rinv) {
  const int row = blockIdx.x;
  const float* tr = t + (size_t)row * DM;
  const int tid = threadIdx.x;  // 64
  float ss = 0.f;
#pragma unroll
  for (int k = 0; k < DM / 64; ++k) {
    const float v = tr[tid + k * 64];
    ss = fmaf(v, v, ss);
  }
  ss += __shfl_xor(ss, 1);
  ss += __shfl_xor(ss, 2);
  ss += __shfl_xor(ss, 4);
  ss += __shfl_xor(ss, 8);
  ss += __shfl_xor(ss, 16);
  ss += __shfl_xor(ss, 32);
  if (tid == 0) rinv[row] = 1.f / sqrtf(ss / DM + 1e-5f);
}

// ---------------- pooled partial sums: part[ch][b][dm] ----------------
__global__ void k_pool(const float* __restrict__ t, const float* __restrict__ rinv,
                       float* __restrict__ part) {
  const int b = blockIdx.x, dmb = blockIdx.y, ch = blockIdx.z;
  const int dm = dmb * 64 + threadIdx.x;
  const int lbeg = ch * (SL / 32);
  float s = 0.f;
  for (int l = lbeg; l < lbeg + SL / 32; ++l)
    s = fmaf(t[((size_t)b * SL + l) * DM + dm], rinv[b * SL + l], s);
  part[((size_t)ch * NB + b) * DM + dm] = s;
}

// ---------------- head: out[b][cls] ----------------
__global__ void k_head(const float* __restrict__ part, const float* __restrict__ norm_w,
                       const float* __restrict__ hw, const float* __restrict__ hb,
                       float* __restrict__ out) {
  const int b = blockIdx.x;
  const int tid = threadIdx.x;  // 64
  __shared__ float pv[DM];
  for (int k = tid; k < DM; k += 64) {
    float s = 0.f;
#pragma unroll
    for (int c = 0; c < 32; ++c) s += part[((size_t)c * NB + b) * DM + k];
    pv[k] = s * norm_w[k] * (1.f / SL);
  }
  __syncthreads();
  const int cls = blockIdx.y * 64 + tid;
  if (cls < NCLS) {
    const float* wr = hw + (size_t)cls * DM;
    float acc = hb[cls];
#pragma unroll 4
    for (int k = 0; k < DM; k += 4) {
      const float4 w4 = *(const float4*)&wr[k];
      acc = fmaf(pv[k], w4.x, acc);
      acc = fmaf(pv[k + 1], w4.y, acc);
      acc = fmaf(pv[k + 2], w4.z, acc);
      acc = fmaf(pv[k + 3], w4.w, acc);
    }
    out[(size_t)b * NCLS + cls] = acc;
  }
}

extern "C" void kernel_launch(void* const* d_in, const int* in_sizes, int n_in,
                              void* d_out, int out_size, void* d_ws, size_t ws_size,
                              hipStream_t stream) {
  (void)in_sizes; (void)n_in; (void)out_size; (void)ws_size;
  const float* x = (const float*)d_in[0];
  const float* patch_w = (const float*)d_in[1];
  const float* patch_b = (const float*)d_in[2];
  const float* in_proj_w = (const float*)d_in[3];
  const float* conv_w = (const float*)d_in[4];
  const float* conv_b = (const float*)d_in[5];
  const float* x_proj_w = (const float*)d_in[6];
  const float* dt_proj_w = (const float*)d_in[7];
  const float* dt_proj_b = (const float*)d_in[8];
  const float* A_log = (const float*)d_in[9];
  const float* Dp = (const float*)d_in[10];
  const float* out_proj_w = (const float*)d_in[11];
  const float* norm_w = (const float*)d_in[12];
  const float* head_w = (const float*)d_in[13];
  const float* head_b = (const float*)d_in[14];

  float* ws = (float*)d_ws;
  size_t o = 0;
  float* t = ws + o;     o += (size_t)NB * SL * DM;
  float* xcT = ws + o;   o += (size_t)NB * DI * SL;
  float* resT = ws + o;  o += (size_t)NB * DI * SL;
  float* uT = ws + o;    o += (size_t)NB * DI * SL;
  float* dbl = ws + o;   o += (size_t)NB * SL * XPN;
  float* dltT = ws + o;  o += (size_t)NB * DI * SL;
  float* yT = ws + o;    o += (size_t)NB * DI * SL;
  float* rinv = ws + o;  o += (size_t)NB * SL;
  float* part = ws + o;  o += (size_t)32 * NB * DM;
  float* hend = ws + o;  o += (size_t)NG * 16;
  float* aprod = ws + o; o += (size_t)NG * 16;
  float* hinit = ws + o; o += (size_t)NG * 16;

  k_patch<<<NB * SL, 128, 0, stream>>>(x, patch_w, patch_b, t);

  for (int i = 0; i < NLAYER; ++i) {
    // in_proj: [R,384] x [1536,384]^T -> xcT (transposed) + resT (transposed)
    k_gemm<1, false, false, 64><<<dim3(196, 24), 256, 0, stream>>>(
        t, in_proj_w + (size_t)i * 2 * DI * DM, nullptr, xcT, resT, DM, DM);
    // depthwise causal conv + silu -> uT
    k_conv<<<(NB * DI * SL) / 256, 256, 0, stream>>>(
        xcT, conv_w + (size_t)i * DI * 4, conv_b + (size_t)i * DI, uT);
    // x_proj: [R,768] x [56,768]^T -> dbl   (A read transposed from uT)
    k_gemm<0, true, false, XPN><<<dim3(196, 1), 256, 0, stream>>>(
        uT, x_proj_w + (size_t)i * XPN * DI, nullptr, dbl, nullptr, DI, 0);
    // dt_proj: [R,24] x [768,24]^T + b -> softplus -> deltaT (transposed)
    k_gemm<2, false, true, 64><<<dim3(196, 12), 256, 0, stream>>>(
        dbl, dt_proj_w + (size_t)i * DI * DR, dt_proj_b + (size_t)i * DI, dltT,
        nullptr, DR, XPN);
    // chunked selective scan + gate -> yT
    k_scan1<<<NG / 16, 256, 0, stream>>>(
        dltT, uT, dbl, A_log + (size_t)i * DI * DSN, hend, aprod);
    k_scanmid<<<(NCHAIN * 16) / 256, 256, 0, stream>>>(hend, aprod, hinit);
    k_scan2<<<NG / 16, 256, 0, stream>>>(
        dltT, uT, dbl, resT, A_log + (size_t)i * DI * DSN, Dp + (size_t)i * DI,
        hinit, yT);
    // out_proj: [R,768] x [384,768]^T (A read transposed from yT), accumulate into t
    k_gemm<3, true, false, 64><<<dim3(196, 6), 256, 0, stream>>>(
        yT, out_proj_w + (size_t)i * DM * DI, nullptr, t, nullptr, DI, 0);
  }

  k_rinv<<<NB * SL, 64, 0, stream>>>(t, rinv);
  k_pool<<<dim3(NB, DM / 64, 32), 64, 0, stream>>>(t, rinv, part);
  k_head<<<dim3(NB, 16), 64, 0, stream>>>(part, norm_w, head_w, head_b, (float*)d_out);
}

// Round 4
// 1756.500 us; speedup vs baseline: 4.7272x; 1.5446x over previous
//
#include <hip/hip_runtime.h>
#include <math.h>

// CausalVisionMamba — bf16-MFMA GEMMs + chunked scan (round 4).
// B=4, L=3136(56x56), D_MODEL=384, D_INNER=768, D_STATE=16, DT_RANK=24, 4 layers.

namespace {
constexpr int NB = 4;
constexpr int SL = 3136;
constexpr int DM = 384;
constexpr int DI = 768;
constexpr int DSN = 16;
constexpr int DR = 24;
constexpr int NLAYER = 4;
constexpr int NCLS = 1000;
constexpr int XPN = DR + 2 * DSN;  // 56
constexpr int CH = 14;
constexpr int CLEN = SL / CH;      // 224
constexpr int NCHAIN = NB * DI;    // 3072
constexpr int NG = NCHAIN * CH;
}

typedef float f32x4 __attribute__((ext_vector_type(4)));
typedef short short8 __attribute__((ext_vector_type(8)));
typedef short short4v __attribute__((ext_vector_type(4)));

__device__ __forceinline__ float siluf(float x) { return x / (1.f + expf(-x)); }
__device__ __forceinline__ float softplusf(float x) {
  return fmaxf(x, 0.f) + log1pf(expf(-fabsf(x)));
}
__device__ __forceinline__ unsigned short cvt_bf(float f) {
  unsigned int x = __float_as_uint(f);
  unsigned int r = (x + 0x7fffu + ((x >> 16) & 1u)) >> 16;  // RNE
  return (unsigned short)r;
}

// ---------------- patch embed: t[b][l][dm] fp32 + tb bf16 ----------------
__global__ void k_patch(const float* __restrict__ x, const float* __restrict__ w,
                        const float* __restrict__ bias, float* __restrict__ t,
                        unsigned short* __restrict__ tb) {
  const int blk = blockIdx.x;
  const int b = blk / SL, l = blk % SL;
  const int hh = l / 56, ww = l % 56;
  __shared__ float patch[48];
  const int tid = threadIdx.x;
  if (tid < 48) {
    const int c = tid / 16, kh = (tid % 16) / 4, kw = tid % 4;
    patch[tid] = x[((size_t)(b * 3 + c) * 224 + (hh * 4 + kh)) * 224 + (ww * 4 + kw)];
  }
  __syncthreads();
  for (int dm = tid; dm < DM; dm += 128) {
    const float* wr = w + (size_t)dm * 48;
    float acc = bias[dm];
#pragma unroll
    for (int p = 0; p < 48; ++p) acc = fmaf(patch[p], wr[p], acc);
    const size_t o = ((size_t)b * SL + l) * DM + dm;
    t[o] = acc;
    tb[o] = cvt_bf(acc);
  }
}

// ---------------- bf16 MFMA GEMM: D = A[M,K](bf16) * W[N,K]^T(fp32->bf16) ----------------
// MEPI 0: x_proj  -> out[m*XPN + n], n < NCAP
// MEPI 1: in_proj -> n<DI: out=xcT [b][n][l]; n>=DI: out2=resT [b][n][l]  (fp32)
// MEPI 2: out_proj-> out[m*DM+n] += acc (t, fp32) and outb[m*DM+n] = bf16(new t)
template <int BM, int BN, int MEPI, int NCAP>
__global__ __launch_bounds__(256) void k_mgemm(
    const unsigned short* __restrict__ A, const float* __restrict__ W,
    float* __restrict__ out, float* __restrict__ out2,
    unsigned short* __restrict__ outb, const int K) {
  constexpr int WM = BM / 2, WN = BN / 2, FM = WM / 16, FN = WN / 16;
  constexpr bool NMASK = (NCAP % BN) != 0;
  __shared__ unsigned short As[BM * 40];
  __shared__ unsigned short Bs[BN * 40];
  const int tid = threadIdx.x;
  const int lane = tid & 63, wave = tid >> 6;
  const int wm = wave >> 1, wn = wave & 1;
  const int m0 = blockIdx.x * BM, n0 = blockIdx.y * BN;
  const int r16 = lane & 15, kg = (lane >> 4) * 8;
  f32x4 acc[FM][FN] = {};
  const int nk = K >> 5;
  for (int kt = 0; kt < nk; ++kt) {
    const int k0 = kt << 5;
    // A staging: bf16 global -> LDS (16B chunks)
#pragma unroll
    for (int it = 0; it < (BM * 4) / 256; ++it) {
      const int c = tid + 256 * it;
      const int row = c >> 2, ks = (c & 3) * 8;
      *(short8*)&As[row * 40 + ks] =
          *(const short8*)&A[(size_t)(m0 + row) * K + k0 + ks];
    }
    // B staging: fp32 global -> cvt -> LDS (4 floats -> 4 bf16)
#pragma unroll
    for (int it = 0; it < (BN * 8) / 256; ++it) {
      const int c = tid + 256 * it;
      const int row = c >> 3, ks = (c & 7) * 4;
      float4 v = make_float4(0.f, 0.f, 0.f, 0.f);
      if (!NMASK || (n0 + row) < NCAP)
        v = *(const float4*)&W[(size_t)(n0 + row) * K + k0 + ks];
      short4v o4;
      o4[0] = (short)cvt_bf(v.x);
      o4[1] = (short)cvt_bf(v.y);
      o4[2] = (short)cvt_bf(v.z);
      o4[3] = (short)cvt_bf(v.w);
      *(short4v*)&Bs[row * 40 + ks] = o4;
    }
    __syncthreads();
    short8 af[FM], bfv[FN];
#pragma unroll
    for (int i = 0; i < FM; ++i)
      af[i] = *(const short8*)&As[(wm * WM + i * 16 + r16) * 40 + kg];
#pragma unroll
    for (int j = 0; j < FN; ++j)
      bfv[j] = *(const short8*)&Bs[(wn * WN + j * 16 + r16) * 40 + kg];
#pragma unroll
    for (int i = 0; i < FM; ++i)
#pragma unroll
      for (int j = 0; j < FN; ++j)
        acc[i][j] = __builtin_amdgcn_mfma_f32_16x16x32_bf16(af[i], bfv[j],
                                                            acc[i][j], 0, 0, 0);
    __syncthreads();
  }

  // Epilogue. C/D layout: col n = lane&15, rows m = (lane>>4)*4 + r.
#pragma unroll
  for (int i = 0; i < FM; ++i) {
#pragma unroll
    for (int j = 0; j < FN; ++j) {
      const int n = n0 + wn * WN + j * 16 + r16;
      const int mb = m0 + wm * WM + i * 16 + ((lane >> 4) << 2);
      f32x4 a = acc[i][j];
      if (MEPI == 0) {
        if (!NMASK || n < NCAP) {
#pragma unroll
          for (int r = 0; r < 4; ++r) out[(size_t)(mb + r) * XPN + n] = a[r];
        }
      } else if (MEPI == 1) {
        float* base = out;
        int nn = n;
        if (n >= DI) { base = out2; nn = n - DI; }
        const int b = mb / SL;
        const int ll = mb - b * SL;
        *(f32x4*)&base[((size_t)(b * DI + nn)) * SL + ll] = a;
      } else {  // MEPI 2
#pragma unroll
        for (int r = 0; r < 4; ++r) {
          const size_t off = (size_t)(mb + r) * DM + n;
          const float nv = out[off] + a[r];
          out[off] = nv;
          outb[off] = cvt_bf(nv);
        }
      }
    }
  }
}

// ---------------- fp32 SIMT GEMM (kept for dt_proj, K=24) ----------------
template <int EPI, bool ATRANS, bool KTAIL, int NCAP>
__global__ __launch_bounds__(256) void k_gemm(
    const float* __restrict__ A, const float* __restrict__ W,
    const float* __restrict__ bias, float* __restrict__ out,
    float* __restrict__ out2, int K, int lda) {
  __shared__ float sm[4352];
  const int tid = threadIdx.x;
  const int m0 = blockIdx.x * 64;
  const int n0 = blockIdx.y * 64;
  const int b = m0 / SL, l0 = m0 % SL;
  const int tm = tid >> 4, tn = tid & 15;
  float acc[4][4] = {};
  float* As = sm;
  float* Ws = sm + 16 * 68;

  const int nk = (K + 15) / 16;
  for (int kt = 0; kt < nk; ++kt) {
    const int k0 = kt * 16;
    {
      const int row = tid >> 2;
      const int kq = (tid & 3) * 4;
      const int kb = k0 + kq;
      float4 v = make_float4(0.f, 0.f, 0.f, 0.f);
      if (!KTAIL || kb < K) v = *(const float4*)&A[(size_t)(m0 + row) * lda + kb];
      As[(kq + 0) * 68 + row] = v.x;
      As[(kq + 1) * 68 + row] = v.y;
      As[(kq + 2) * 68 + row] = v.z;
      As[(kq + 3) * 68 + row] = v.w;
    }
    {
      const int row = tid >> 2;
      const int kq = (tid & 3) * 4;
      const int kb = k0 + kq;
      float4 v = make_float4(0.f, 0.f, 0.f, 0.f);
      const bool nok = (NCAP % 64 == 0) || (n0 + row < NCAP);
      if (nok && (!KTAIL || kb < K)) v = *(const float4*)&W[(size_t)(n0 + row) * K + kb];
      Ws[(kq + 0) * 68 + row] = v.x;
      Ws[(kq + 1) * 68 + row] = v.y;
      Ws[(kq + 2) * 68 + row] = v.z;
      Ws[(kq + 3) * 68 + row] = v.w;
    }
    __syncthreads();
#pragma unroll
    for (int kk = 0; kk < 16; ++kk) {
      const float4 av = *(const float4*)&As[kk * 68 + 4 * tm];
      const float4 wv = *(const float4*)&Ws[kk * 68 + 4 * tn];
      const float ax[4] = {av.x, av.y, av.z, av.w};
      const float wx[4] = {wv.x, wv.y, wv.z, wv.w};
#pragma unroll
      for (int i = 0; i < 4; ++i)
#pragma unroll
        for (int j = 0; j < 4; ++j) acc[i][j] = fmaf(ax[i], wx[j], acc[i][j]);
    }
    __syncthreads();
  }

  // transpose epilogue through LDS -> [b][n][l] (EPI==2: softplus+bias)
#pragma unroll
  for (int j = 0; j < 4; ++j) {
    const int nn = 4 * tn + j;
#pragma unroll
    for (int i = 0; i < 4; ++i) {
      float v = acc[i][j];
      if (EPI == 2) v = softplusf(v + bias[n0 + nn]);
      sm[nn * 68 + 4 * tm + i] = v;
    }
  }
  __syncthreads();
  const int row = tid >> 2;
  const int seg = (tid & 3) * 16;
  const float* src = &sm[row * 68 + seg];
  float* dst = out + ((size_t)(b * DI + n0 + row)) * SL + l0 + seg;
#pragma unroll
  for (int q = 0; q < 4; ++q) {
    *(float4*)&dst[q * 4] = *(const float4*)&src[q * 4];
  }
}

// ---------------- depthwise causal conv1d + bias + silu: uT[b][d][l] ----------------
__global__ void k_conv(const float* __restrict__ xcT, const float* __restrict__ cw,
                       const float* __restrict__ cb, float* __restrict__ uT) {
  const size_t idx = (size_t)blockIdx.x * 256 + threadIdx.x;
  const int l = (int)(idx % SL);
  const int bd = (int)(idx / SL);
  const int d = bd % DI;
  const float* row = xcT + (size_t)bd * SL;
  const float4 w = *(const float4*)&cw[d * 4];
  float acc = cb[d] + w.w * row[l];
  if (l >= 1) acc = fmaf(w.z, row[l - 1], acc);
  if (l >= 2) acc = fmaf(w.y, row[l - 2], acc);
  if (l >= 3) acc = fmaf(w.x, row[l - 3], acc);
  uT[idx] = siluf(acc);
}

// ---------------- transpose+cvt: X [NB*DI][SL] fp32 -> Y [NB*SL][DI] bf16 ----------------
__global__ __launch_bounds__(256) void k_tcvt(const float* __restrict__ X,
                                              unsigned short* __restrict__ Y) {
  const int l0 = blockIdx.x * 64, d0 = blockIdx.y * 64, b = blockIdx.z;
  __shared__ float sm[64 * 68];
  const int tid = threadIdx.x;
  {
    const int dr = tid >> 2, ls = (tid & 3) * 16;
    const float* src = &X[((size_t)(b * DI + d0 + dr)) * SL + l0 + ls];
    const int sw = ((dr >> 4) & 3) << 2;
#pragma unroll
    for (int q = 0; q < 4; ++q) {
      *(float4*)&sm[dr * 68 + ((ls + q * 4) ^ sw)] = *(const float4*)&src[q * 4];
    }
  }
  __syncthreads();
  {
    const int lr = tid >> 2, dsg = (tid & 3) * 16;
    short8 v0, v1;
#pragma unroll
    for (int j = 0; j < 8; ++j) {
      const int d = dsg + j;
      v0[j] = (short)cvt_bf(sm[d * 68 + (lr ^ (((d >> 4) & 3) << 2))]);
    }
#pragma unroll
    for (int j = 0; j < 8; ++j) {
      const int d = dsg + 8 + j;
      v1[j] = (short)cvt_bf(sm[d * 68 + (lr ^ (((d >> 4) & 3) << 2))]);
    }
    unsigned short* dst = &Y[((size_t)(b * SL + l0 + lr)) * DI + d0 + dsg];
    *(short8*)&dst[0] = v0;
    *(short8*)&dst[8] = v1;
  }
}

// ---------------- chunked selective scan ----------------
__global__ __launch_bounds__(256) void k_scan1(
    const float* __restrict__ deltaT, const float* __restrict__ uT,
    const float* __restrict__ dbl, const float* __restrict__ A_log,
    float* __restrict__ hend, float* __restrict__ aprod) {
  const int tid = threadIdx.x;
  const int n = tid & 15, g = tid >> 4;
  const int gidx = blockIdx.x * 16 + g;
  const int chain = gidx / CH, c = gidx % CH;
  const int b = chain / DI, d = chain % DI;
  const float a2 = -expf(A_log[d * DSN + n]) * 1.44269504088896341f;
  const int base = c * CLEN;
  const float* drow = deltaT + (size_t)chain * SL + base;
  const float* urow = uT + (size_t)chain * SL + base;
  const float* dblb = dbl + (size_t)b * SL * XPN + (size_t)base * XPN;
  float h = 0.f, dsum = 0.f;
  for (int l0 = 0; l0 < CLEN; l0 += 8) {
    const float4 dv0 = *(const float4*)&drow[l0];
    const float4 dv1 = *(const float4*)&drow[l0 + 4];
    const float4 uv0 = *(const float4*)&urow[l0];
    const float4 uv1 = *(const float4*)&urow[l0 + 4];
    float Bv[8];
#pragma unroll
    for (int j = 0; j < 8; ++j) Bv[j] = dblb[(size_t)(l0 + j) * XPN + DR + n];
    const float dvv[8] = {dv0.x, dv0.y, dv0.z, dv0.w, dv1.x, dv1.y, dv1.z, dv1.w};
    const float uvv[8] = {uv0.x, uv0.y, uv0.z, uv0.w, uv1.x, uv1.y, uv1.z, uv1.w};
#pragma unroll
    for (int j = 0; j < 8; ++j) {
      const float dl = dvv[j];
      const float da = exp2f(dl * a2);
      h = fmaf(da, h, dl * uvv[j] * Bv[j]);
      dsum += dl;
    }
  }
  hend[(size_t)gidx * 16 + n] = h;
  aprod[(size_t)gidx * 16 + n] = exp2f(a2 * dsum);
}

__global__ __launch_bounds__(256) void k_scanmid(
    const float* __restrict__ hend, const float* __restrict__ aprod,
    float* __restrict__ hinit) {
  const int gid = blockIdx.x * 256 + threadIdx.x;
  const int chain = gid >> 4, n = gid & 15;
  float H = 0.f;
  for (int c = 0; c < CH; ++c) {
    const size_t o = ((size_t)chain * CH + c) * 16 + n;
    hinit[o] = H;
    H = fmaf(aprod[o], H, hend[o]);
  }
}

__global__ __launch_bounds__(256) void k_scan2(
    const float* __restrict__ deltaT, const float* __restrict__ uT,
    const float* __restrict__ dbl, const float* __restrict__ resT,
    const float* __restrict__ A_log, const float* __restrict__ Dp,
    const float* __restrict__ hinit, float* __restrict__ yT) {
  const int tid = threadIdx.x;
  const int n = tid & 15, g = tid >> 4;
  const int gidx = blockIdx.x * 16 + g;
  const int chain = gidx / CH, c = gidx % CH;
  const int b = chain / DI, d = chain % DI;
  const float a2 = -expf(A_log[d * DSN + n]) * 1.44269504088896341f;
  const float dp = Dp[d];
  const int base = c * CLEN;
  const float* drow = deltaT + (size_t)chain * SL + base;
  const float* urow = uT + (size_t)chain * SL + base;
  const float* dblb = dbl + (size_t)b * SL * XPN + (size_t)base * XPN;
  const float* resb = resT + (size_t)chain * SL + base;
  float* yb = yT + (size_t)chain * SL + base;
  float h = hinit[(size_t)gidx * 16 + n];
  for (int l0 = 0; l0 < CLEN; l0 += 8) {
    const float4 dv0 = *(const float4*)&drow[l0];
    const float4 dv1 = *(const float4*)&drow[l0 + 4];
    const float4 uv0 = *(const float4*)&urow[l0];
    const float4 uv1 = *(const float4*)&urow[l0 + 4];
    float Bv[8], Cv[8];
#pragma unroll
    for (int j = 0; j < 8; ++j) {
      Bv[j] = dblb[(size_t)(l0 + j) * XPN + DR + n];
      Cv[j] = dblb[(size_t)(l0 + j) * XPN + DR + DSN + n];
    }
    const float dvv[8] = {dv0.x, dv0.y, dv0.z, dv0.w, dv1.x, dv1.y, dv1.z, dv1.w};
    const float uvv[8] = {uv0.x, uv0.y, uv0.z, uv0.w, uv1.x, uv1.y, uv1.z, uv1.w};
    float p[8];
#pragma unroll
    for (int j = 0; j < 8; ++j) {
      const float dl = dvv[j];
      const float da = exp2f(dl * a2);
      h = fmaf(da, h, dl * uvv[j] * Bv[j]);
      p[j] = h * Cv[j];
    }
#pragma unroll
    for (int j = 0; j < 8; ++j) p[j] += __shfl_xor(p[j], 1);
#pragma unroll
    for (int j = 0; j < 8; ++j) p[j] += __shfl_xor(p[j], 2);
#pragma unroll
    for (int j = 0; j < 8; ++j) p[j] += __shfl_xor(p[j], 4);
#pragma unroll
    for (int j = 0; j < 8; ++j) p[j] += __shfl_xor(p[j], 8);
    float myp = p[0], myu = uvv[0];
#pragma unroll
    for (int j = 1; j < 8; ++j) {
      const bool e = (n == j);
      myp = e ? p[j] : myp;
      myu = e ? uvv[j] : myu;
    }
    if (n < 8) {
      const float r = resb[l0 + n];
      yb[l0 + n] = (myp + myu * dp) * siluf(r);
    }
  }
}

// ---------------- RMS denom ----------------
__global__ void k_rinv(const float* __restrict__ t, float* __restrict__ rinv) {
  const int row = blockIdx.x;
  const float* tr = t + (size_t)row * DM;
  const int tid = threadIdx.x;
  float ss = 0.f;
#pragma unroll
  for (int k = 0; k < DM / 64; ++k) {
    const float v = tr[tid + k * 64];
    ss = fmaf(v, v, ss);
  }
  ss += __shfl_xor(ss, 1);
  ss += __shfl_xor(ss, 2);
  ss += __shfl_xor(ss, 4);
  ss += __shfl_xor(ss, 8);
  ss += __shfl_xor(ss, 16);
  ss += __shfl_xor(ss, 32);
  if (tid == 0) rinv[row] = 1.f / sqrtf(ss / DM + 1e-5f);
}

// ---------------- pooled partial sums ----------------
__global__ void k_pool(const float* __restrict__ t, const float* __restrict__ rinv,
                       float* __restrict__ part) {
  const int b = blockIdx.x, dmb = blockIdx.y, ch = blockIdx.z;
  const int dm = dmb * 64 + threadIdx.x;
  const int lbeg = ch * (SL / 32);
  float s = 0.f;
  for (int l = lbeg; l < lbeg + SL / 32; ++l)
    s = fmaf(t[((size_t)b * SL + l) * DM + dm], rinv[b * SL + l], s);
  part[((size_t)ch * NB + b) * DM + dm] = s;
}

// ---------------- head ----------------
__global__ void k_head(const float* __restrict__ part, const float* __restrict__ norm_w,
                       const float* __restrict__ hw, const float* __restrict__ hb,
                       float* __restrict__ out) {
  const int b = blockIdx.x;
  const int tid = threadIdx.x;
  __shared__ float pv[DM];
  for (int k = tid; k < DM; k += 64) {
    float s = 0.f;
#pragma unroll
    for (int c = 0; c < 32; ++c) s += part[((size_t)c * NB + b) * DM + k];
    pv[k] = s * norm_w[k] * (1.f / SL);
  }
  __syncthreads();
  const int cls = blockIdx.y * 64 + tid;
  if (cls < NCLS) {
    const float* wr = hw + (size_t)cls * DM;
    float acc = hb[cls];
#pragma unroll 4
    for (int k = 0; k < DM; k += 4) {
      const float4 w4 = *(const float4*)&wr[k];
      acc = fmaf(pv[k], w4.x, acc);
      acc = fmaf(pv[k + 1], w4.y, acc);
      acc = fmaf(pv[k + 2], w4.z, acc);
      acc = fmaf(pv[k + 3], w4.w, acc);
    }
    out[(size_t)b * NCLS + cls] = acc;
  }
}

extern "C" void kernel_launch(void* const* d_in, const int* in_sizes, int n_in,
                              void* d_out, int out_size, void* d_ws, size_t ws_size,
                              hipStream_t stream) {
  (void)in_sizes; (void)n_in; (void)out_size; (void)ws_size;
  const float* x = (const float*)d_in[0];
  const float* patch_w = (const float*)d_in[1];
  const float* patch_b = (const float*)d_in[2];
  const float* in_proj_w = (const float*)d_in[3];
  const float* conv_w = (const float*)d_in[4];
  const float* conv_b = (const float*)d_in[5];
  const float* x_proj_w = (const float*)d_in[6];
  const float* dt_proj_w = (const float*)d_in[7];
  const float* dt_proj_b = (const float*)d_in[8];
  const float* A_log = (const float*)d_in[9];
  const float* Dp = (const float*)d_in[10];
  const float* out_proj_w = (const float*)d_in[11];
  const float* norm_w = (const float*)d_in[12];
  const float* head_w = (const float*)d_in[13];
  const float* head_b = (const float*)d_in[14];

  float* ws = (float*)d_ws;
  size_t o = 0;
  float* t = ws + o;     o += (size_t)NB * SL * DM;
  float* xcT = ws + o;   o += (size_t)NB * DI * SL;   // reused: u_bf + y_bf (bf16)
  float* resT = ws + o;  o += (size_t)NB * DI * SL;
  float* uT = ws + o;    o += (size_t)NB * DI * SL;
  float* dbl = ws + o;   o += (size_t)NB * SL * XPN;
  float* dltT = ws + o;  o += (size_t)NB * DI * SL;
  float* yT = ws + o;    o += (size_t)NB * DI * SL;
  float* rinv = ws + o;  o += (size_t)NB * SL;
  float* part = ws + o;  o += (size_t)32 * NB * DM;
  float* hend = ws + o;  o += (size_t)NG * 16;
  float* aprod = ws + o; o += (size_t)NG * 16;
  float* hinit = ws + o; o += (size_t)NG * 16;
  unsigned short* tb = (unsigned short*)(ws + o); o += (size_t)NB * SL * DM / 2;

  // u_bf / y_bf alias xcT (dead after k_conv); each is NB*SL*DI bf16.
  unsigned short* u_bf = (unsigned short*)xcT;
  unsigned short* y_bf = u_bf + (size_t)NB * SL * DI;

  k_patch<<<NB * SL, 128, 0, stream>>>(x, patch_w, patch_b, t, tb);

  for (int i = 0; i < NLAYER; ++i) {
    // in_proj: tb[M,384](bf16) x W[1536,384]^T -> xcT / resT (fp32, [b][n][l])
    k_mgemm<128, 128, 1, 1536><<<dim3(98, 12), 256, 0, stream>>>(
        tb, in_proj_w + (size_t)i * 2 * DI * DM, xcT, resT, nullptr, DM);
    // depthwise causal conv + silu -> uT (fp32)
    k_conv<<<(NB * DI * SL) / 256, 256, 0, stream>>>(
        xcT, conv_w + (size_t)i * DI * 4, conv_b + (size_t)i * DI, uT);
    // uT -> u_bf [M,768] bf16 (xcT now dead)
    k_tcvt<<<dim3(49, 12, NB), 256, 0, stream>>>(uT, u_bf);
    // x_proj: u_bf x W[56,768]^T -> dbl [M,56] fp32
    k_mgemm<64, 64, 0, XPN><<<dim3(196, 1), 256, 0, stream>>>(
        u_bf, x_proj_w + (size_t)i * XPN * DI, dbl, nullptr, nullptr, DI);
    // dt_proj (fp32 SIMT): softplus(dbl[:,:24] @ dt_w^T + b) -> dltT [b][d][l]
    k_gemm<2, false, true, 64><<<dim3(196, 12), 256, 0, stream>>>(
        dbl, dt_proj_w + (size_t)i * DI * DR, dt_proj_b + (size_t)i * DI, dltT,
        nullptr, DR, XPN);
    // chunked selective scan + gate -> yT (fp32)
    k_scan1<<<NG / 16, 256, 0, stream>>>(
        dltT, uT, dbl, A_log + (size_t)i * DI * DSN, hend, aprod);
    k_scanmid<<<(NCHAIN * 16) / 256, 256, 0, stream>>>(hend, aprod, hinit);
    k_scan2<<<NG / 16, 256, 0, stream>>>(
        dltT, uT, dbl, resT, A_log + (size_t)i * DI * DSN, Dp + (size_t)i * DI,
        hinit, yT);
    // yT -> y_bf [M,768] bf16
    k_tcvt<<<dim3(49, 12, NB), 256, 0, stream>>>(yT, y_bf);
    // out_proj: y_bf x W[384,768]^T -> t += ; tb = bf16(t)
    k_mgemm<128, 128, 2, 384><<<dim3(98, 3), 256, 0, stream>>>(
        y_bf, out_proj_w + (size_t)i * DM * DI, t, nullptr, tb, DI);
  }

  k_rinv<<<NB * SL, 64, 0, stream>>>(t, rinv);
  k_pool<<<dim3(NB, DM / 64, 32), 64, 0, stream>>>(t, rinv, part);
  k_head<<<dim3(NB, 16), 64, 0, stream>>>(part, norm_w, head_w, head_b, (float*)d_out);
}